// Round 6
// baseline (246.891 us; speedup 1.0000x reference)
//
#include <hip/hip_runtime.h>
#include <hip/hip_bf16.h>

typedef __attribute__((ext_vector_type(8))) short bf16x8;
typedef __attribute__((ext_vector_type(4))) float f32x4;

__device__ __forceinline__ unsigned short f2bf(float f) {
    unsigned x = __float_as_uint(f);
    unsigned r = (x + 0x7FFF + ((x >> 16) & 1)) >> 16;   // RNE
    return (unsigned short)r;
}
__device__ __forceinline__ bf16x8 cvt8(const float* __restrict__ p) {
    bf16x8 r;
#pragma unroll
    for (int j = 0; j < 8; ++j) r[j] = (short)f2bf(p[j]);
    return r;
}
// packed: one dword holds bf16 elems {lo=2j, hi=2j+1}; h = relu(y+z) repacked
__device__ __forceinline__ unsigned pack_relu_bf16(unsigned yv, unsigned zv) {
    float ylo = __uint_as_float(yv << 16);
    float yhi = __uint_as_float(yv & 0xFFFF0000u);
    float zlo = __uint_as_float(zv << 16);
    float zhi = __uint_as_float(zv & 0xFFFF0000u);
    float lo = fmaxf(ylo + zlo, 0.0f);
    float hi = fmaxf(yhi + zhi, 0.0f);
    __hip_bfloat162 p = __float22bfloat162_rn(float2{lo, hi});
    return *(unsigned*)&p;
}

// ---------------- kernel 0a: weight prep (bf16 transpose to n-major) ------------
__global__ void prep_k(const float* __restrict__ w1,
                       const float* __restrict__ w2,
                       unsigned short* __restrict__ w1t,
                       unsigned short* __restrict__ w2t) {
    int t = threadIdx.x;
    for (int i = t; i < 128 * 64; i += 256) {
        int k = i >> 6, n = i & 63;
        w1t[n * 128 + k] = f2bf(w1[i]);
    }
    for (int i = t; i < 64 * 64; i += 256) {
        int k = i >> 6, n = i & 63;
        w2t[n * 64 + k] = f2bf(w2[i]);
    }
}

// ---------------- kernel 0c: segment offsets via parallel binary search ---------
__global__ void bounds_k(const int* __restrict__ segs, int* __restrict__ seg_off,
                         int N, int E) {
    int t = blockIdx.x * blockDim.x + threadIdx.x;
    if (t > N) return;
    int l = 0, r = E;
    while (l < r) { int mid = (l + r) >> 1; if (segs[mid] < t) l = mid + 1; else r = mid; }
    seg_off[t] = l;
}

// ---------------- kernel 0d: fused u2e->bf16 convert + Y = u2e @ W1_top ---------
// One wave per 16 rows. Emits u2ebf AND Y (bf16).
__launch_bounds__(256)
__global__ void conv_y_k(const float* __restrict__ u2e,
                         const unsigned short* __restrict__ w1t,
                         unsigned short* __restrict__ u2ebf,
                         unsigned short* __restrict__ Y, int V) {
    const int wid = threadIdx.x >> 6;
    const int lane = threadIdx.x & 63;
    const int q = lane >> 4;
    const int m15 = lane & 15;
    const int wbase = (blockIdx.x * 4 + wid) * 16;
    if (wbase >= V) return;
    int row = min(wbase + m15, V - 1);

    const float* p = u2e + (long)row * 64;
    bf16x8 a0 = cvt8(p + q * 8);
    bf16x8 a1 = cvt8(p + 32 + q * 8);
    // write-back converted row (valid lanes only to avoid double-write races)
    if (wbase + m15 < V) {
        *(bf16x8*)(u2ebf + (long)row * 64 + q * 8) = a0;
        *(bf16x8*)(u2ebf + (long)row * 64 + 32 + q * 8) = a1;
    }

    f32x4 acc[4];
#pragma unroll
    for (int b = 0; b < 4; ++b) {
        acc[b] = (f32x4){0.f, 0.f, 0.f, 0.f};
        const bf16x8* wrow = (const bf16x8*)(w1t + (b * 16 + m15) * 128);
        acc[b] = __builtin_amdgcn_mfma_f32_16x16x32_bf16(a0, wrow[0 + q], acc[b], 0, 0, 0);
        acc[b] = __builtin_amdgcn_mfma_f32_16x16x32_bf16(a1, wrow[4 + q], acc[b], 0, 0, 0);
    }
#pragma unroll
    for (int b = 0; b < 4; ++b)
#pragma unroll
        for (int r = 0; r < 4; ++r) {
            int rr = wbase + q * 4 + r;
            if (rr < V) Y[(long)rr * 64 + b * 16 + m15] = f2bf(acc[b][r]);
        }
}

// ---------------- kernel 0d': Y only, from f32 (tier-2) -------------------------
__launch_bounds__(256)
__global__ void y_k(const float* __restrict__ u2e,
                    const unsigned short* __restrict__ w1t,
                    unsigned short* __restrict__ Y, int V) {
    const int wid = threadIdx.x >> 6;
    const int lane = threadIdx.x & 63;
    const int q = lane >> 4;
    const int m15 = lane & 15;
    const int wbase = (blockIdx.x * 4 + wid) * 16;
    if (wbase >= V) return;
    int row = min(wbase + m15, V - 1);
    const float* p = u2e + (long)row * 64;
    bf16x8 a0 = cvt8(p + q * 8);
    bf16x8 a1 = cvt8(p + 32 + q * 8);
    f32x4 acc[4];
#pragma unroll
    for (int b = 0; b < 4; ++b) {
        acc[b] = (f32x4){0.f, 0.f, 0.f, 0.f};
        const bf16x8* wrow = (const bf16x8*)(w1t + (b * 16 + m15) * 128);
        acc[b] = __builtin_amdgcn_mfma_f32_16x16x32_bf16(a0, wrow[0 + q], acc[b], 0, 0, 0);
        acc[b] = __builtin_amdgcn_mfma_f32_16x16x32_bf16(a1, wrow[4 + q], acc[b], 0, 0, 0);
    }
#pragma unroll
    for (int b = 0; b < 4; ++b)
#pragma unroll
        for (int r = 0; r < 4; ++r) {
            int rr = wbase + q * 4 + r;
            if (rr < V) Y[(long)rr * 64 + b * 16 + m15] = f2bf(acc[b][r]);
        }
}

// ---------------- kernel 0e: z[n] = u2e[nodes[n]] @ W1_bot + b1 (bf16 out) ------
template <bool BF>
__launch_bounds__(256)
__global__ void z_k(const int* __restrict__ nodes,
                    const unsigned short* __restrict__ u2ebf,
                    const float* __restrict__ u2e,
                    const unsigned short* __restrict__ w1t,
                    const float* __restrict__ b1f,
                    unsigned short* __restrict__ z, int N) {
    const int wid = threadIdx.x >> 6;
    const int lane = threadIdx.x & 63;
    const int q = lane >> 4;
    const int m15 = lane & 15;
    const int wbase = (blockIdx.x * 4 + wid) * 16;
    if (wbase >= N) return;
    int nd = nodes[min(wbase + m15, N - 1)];

    bf16x8 a0, a1;
    if constexpr (BF) {
        const unsigned short* p = u2ebf + (long)nd * 64;
        a0 = *(const bf16x8*)(p + q * 8);
        a1 = *(const bf16x8*)(p + 32 + q * 8);
    } else {
        const float* p = u2e + (long)nd * 64;
        a0 = cvt8(p + q * 8);
        a1 = cvt8(p + 32 + q * 8);
    }
    f32x4 acc[4];
#pragma unroll
    for (int b = 0; b < 4; ++b) {
        float bv = b1f[b * 16 + m15];
        acc[b] = (f32x4){bv, bv, bv, bv};
        const bf16x8* wrow = (const bf16x8*)(w1t + (b * 16 + m15) * 128);
        acc[b] = __builtin_amdgcn_mfma_f32_16x16x32_bf16(a0, wrow[8 + q], acc[b], 0, 0, 0);
        acc[b] = __builtin_amdgcn_mfma_f32_16x16x32_bf16(a1, wrow[12 + q], acc[b], 0, 0, 0);
    }
#pragma unroll
    for (int b = 0; b < 4; ++b)
#pragma unroll
        for (int r = 0; r < 4; ++r) {
            int rr = wbase + q * 4 + r;
            if (rr < N) z[(long)rr * 64 + b * 16 + m15] = f2bf(acc[b][r]);
        }
}

// ---------------- kernel 1 (fused): per-node MLP + softmax + aggregation --------
// One block per node. Chunk of 64 edges: phase A (4 waves x 16 edges): h1 =
// relu(Y[neigh]+z[n]) in-register -> MFMA layer2 -> layer3 -> exL in LDS.
// Phase B: weighted gather-sum using exL/idxL. Normalize by sum(ex) at end.
template <bool BF>
__launch_bounds__(256)
__global__ void fused_k(const int* __restrict__ seg_off,
                        const int* __restrict__ neigh,
                        const unsigned short* __restrict__ Y,
                        const unsigned short* __restrict__ z,
                        const unsigned short* __restrict__ u2ebf,
                        const float* __restrict__ u2e,
                        const unsigned short* __restrict__ w2t,
                        const float* __restrict__ b2f,
                        const float* __restrict__ w3f, const float* __restrict__ b3f,
                        float* __restrict__ out, int N) {
    __shared__ float exL[64];
    __shared__ int idxL[64];
    __shared__ float part[4][64];
    __shared__ float redbuf[4];

    const int n = blockIdx.x;
    const int t = threadIdx.x;
    const int wid = t >> 6;
    const int lane = t & 63;
    const int q = lane >> 4;
    const int m15 = lane & 15;
    const int lo = seg_off[n];
    const int hi = seg_off[n + 1];
    const int deg = hi - lo;
    const int nchunk = (deg + 63) >> 6;

    // node's z row, A-layout chunks (L1-broadcast across waves)
    const unsigned short* zr = z + (long)n * 64;
    bf16x8 z0 = *(const bf16x8*)(zr + q * 8);
    bf16x8 z1 = *(const bf16x8*)(zr + 32 + q * 8);

    const int slot = t >> 5;        // 0..7
    const int c = lane & 31;        // channel-pair
    const float b3v = b3f[0];

    float ax = 0.0f, ay = 0.0f, s = 0.0f;

    for (int ck = 0; ck < nchunk; ++ck) {
        const int cs = lo + ck * 64;
        const int clen = min(64, hi - cs);

        // ---- phase A: MLP for this wave's 16 edges
        if (t < clen) idxL[t] = neigh[cs + t];
        const int rbase = wid * 16;           // chunk-row base for this wave
        if (rbase < clen) {
            int e = cs + rbase + m15;
            int ec = min(e, hi - 1);
            int vi = neigh[ec];
            const unsigned short* yr = Y + (long)vi * 64;
            bf16x8 y0 = *(const bf16x8*)(yr + q * 8);
            bf16x8 y1 = *(const bf16x8*)(yr + 32 + q * 8);

            bf16x8 h0, h1;
#pragma unroll
            for (int j = 0; j < 4; ++j) {
                ((unsigned*)&h0)[j] = pack_relu_bf16(((unsigned*)&y0)[j], ((unsigned*)&z0)[j]);
                ((unsigned*)&h1)[j] = pack_relu_bf16(((unsigned*)&y1)[j], ((unsigned*)&z1)[j]);
            }

            f32x4 acc2[4];
#pragma unroll
            for (int b = 0; b < 4; ++b) {
                float bv = b2f[b * 16 + m15];
                acc2[b] = (f32x4){bv, bv, bv, bv};
                const bf16x8* wrow = (const bf16x8*)(w2t + (b * 16 + m15) * 64);
                acc2[b] = __builtin_amdgcn_mfma_f32_16x16x32_bf16(h0, wrow[0 + q], acc2[b], 0, 0, 0);
                acc2[b] = __builtin_amdgcn_mfma_f32_16x16x32_bf16(h1, wrow[4 + q], acc2[b], 0, 0, 0);
            }
#pragma unroll
            for (int r = 0; r < 4; ++r) {
                float v = 0.0f;
#pragma unroll
                for (int b = 0; b < 4; ++b) v += fmaxf(acc2[b][r], 0.0f) * w3f[b * 16 + m15];
                v += __shfl_xor(v, 1);
                v += __shfl_xor(v, 2);
                v += __shfl_xor(v, 4);
                v += __shfl_xor(v, 8);
                int row = rbase + q * 4 + r;
                if (m15 == r && row < clen) exL[row] = __expf(v + b3v);
            }
        }
        __syncthreads();

        // ---- phase B: weighted gather-sum of this chunk
        for (int j = slot; j < clen; j += 8) {
            float a = exL[j];
            int vi = idxL[j];
            if constexpr (BF) {
                unsigned v = *(const unsigned*)(u2ebf + (long)vi * 64 + c * 2);
                ax = fmaf(a, __uint_as_float(v << 16), ax);
                ay = fmaf(a, __uint_as_float(v & 0xFFFF0000u), ay);
            } else {
                float2 v = *(const float2*)(u2e + (long)vi * 64 + c * 2);
                ax = fmaf(a, v.x, ax);
                ay = fmaf(a, v.y, ay);
            }
            s += a;
        }
        __syncthreads();
    }

    // ---- epilogue: fold + normalize
    ax += __shfl_xor(ax, 32);
    ay += __shfl_xor(ay, 32);
    if (lane < 32) {
        part[wid][c * 2] = ax;
        part[wid][c * 2 + 1] = ay;
    }
    s = ((lane & 31) == 0) ? s : 0.0f;
    s += __shfl_xor(s, 32);
    s += __shfl_xor(s, 16);
    s += __shfl_xor(s, 8);
    s += __shfl_xor(s, 4);
    s += __shfl_xor(s, 2);
    s += __shfl_xor(s, 1);
    if (lane == 0) redbuf[wid] = s;
    __syncthreads();
    if (t < 64) {
        float stot = redbuf[0] + redbuf[1] + redbuf[2] + redbuf[3];
        float inv = 1.0f / fmaxf(stot, 1e-9f);
        out[(long)n * 64 + t] =
            (part[0][t] + part[1][t] + part[2][t] + part[3][t]) * inv;
    }
}

// ---------------- tier-3 fallback (tiny ws): round-5 style ----------------------
__launch_bounds__(256)
__global__ void logits_fb_k(const int* __restrict__ nodes,
                            const int* __restrict__ neigh,
                            const int* __restrict__ segs,
                            const float* __restrict__ u2e,
                            const unsigned short* __restrict__ w1t,
                            const unsigned short* __restrict__ w2t,
                            const float* __restrict__ b1f, const float* __restrict__ b2f,
                            const float* __restrict__ w3f, const float* __restrict__ b3f,
                            float* __restrict__ ex, int E) {
    __shared__ __align__(16) unsigned short h1buf[4][16 * 72];
    const int wid = threadIdx.x >> 6;
    const int lane = threadIdx.x & 63;
    const int q = lane >> 4;
    const int m15 = lane & 15;
    const long base = ((long)blockIdx.x * 4 + wid) * 16;
    long ee0 = base + m15;
    int e = (int)(ee0 < E ? ee0 : (long)E - 1);
    int ni = neigh[e];
    int ctr = nodes[segs[e]];
    const float* eu = u2e + (long)ni * 64;
    const float* ur = u2e + (long)ctr * 64;
    bf16x8 a0 = cvt8(eu + q * 8), a1 = cvt8(eu + 32 + q * 8);
    bf16x8 a2 = cvt8(ur + q * 8), a3 = cvt8(ur + 32 + q * 8);
    f32x4 acc[4];
#pragma unroll
    for (int b = 0; b < 4; ++b) {
        float bv = b1f[b * 16 + m15];
        acc[b] = (f32x4){bv, bv, bv, bv};
        const bf16x8* wrow = (const bf16x8*)(w1t + (b * 16 + m15) * 128);
        acc[b] = __builtin_amdgcn_mfma_f32_16x16x32_bf16(a0, wrow[0 + q], acc[b], 0, 0, 0);
        acc[b] = __builtin_amdgcn_mfma_f32_16x16x32_bf16(a1, wrow[4 + q], acc[b], 0, 0, 0);
        acc[b] = __builtin_amdgcn_mfma_f32_16x16x32_bf16(a2, wrow[8 + q], acc[b], 0, 0, 0);
        acc[b] = __builtin_amdgcn_mfma_f32_16x16x32_bf16(a3, wrow[12 + q], acc[b], 0, 0, 0);
    }
#pragma unroll
    for (int b = 0; b < 4; ++b)
#pragma unroll
        for (int r = 0; r < 4; ++r)
            h1buf[wid][(q * 4 + r) * 72 + b * 16 + m15] = f2bf(fmaxf(acc[b][r], 0.0f));
    const unsigned short* hrow = &h1buf[wid][m15 * 72];
    bf16x8 h0 = *(const bf16x8*)(hrow + q * 8);
    bf16x8 h1 = *(const bf16x8*)(hrow + 32 + q * 8);
    f32x4 acc2[4];
#pragma unroll
    for (int b = 0; b < 4; ++b) {
        float bv = b2f[b * 16 + m15];
        acc2[b] = (f32x4){bv, bv, bv, bv};
        const bf16x8* wrow = (const bf16x8*)(w2t + (b * 16 + m15) * 64);
        acc2[b] = __builtin_amdgcn_mfma_f32_16x16x32_bf16(h0, wrow[0 + q], acc2[b], 0, 0, 0);
        acc2[b] = __builtin_amdgcn_mfma_f32_16x16x32_bf16(h1, wrow[4 + q], acc2[b], 0, 0, 0);
    }
    float b3v = b3f[0];
#pragma unroll
    for (int r = 0; r < 4; ++r) {
        float v = 0.0f;
#pragma unroll
        for (int b = 0; b < 4; ++b) v += fmaxf(acc2[b][r], 0.0f) * w3f[b * 16 + m15];
        v += __shfl_xor(v, 1);
        v += __shfl_xor(v, 2);
        v += __shfl_xor(v, 4);
        v += __shfl_xor(v, 8);
        long ee = base + q * 4 + r;
        if (m15 == r && ee < E) ex[ee] = __expf(v + b3v);
    }
}

__launch_bounds__(256)
__global__ void agg_fb_k(const int* __restrict__ seg_off,
                         const int* __restrict__ neigh,
                         const float* __restrict__ u2e,
                         const float* __restrict__ ex,
                         float* __restrict__ out, int N) {
    __shared__ float part[4][64];
    __shared__ float redbuf[4];
    const int n = blockIdx.x;
    const int t = threadIdx.x;
    const int wid = t >> 6;
    const int lane = t & 63;
    const int lo = seg_off[n], hi = seg_off[n + 1];
    const int slot = t >> 5;
    const int c = lane & 31;
    float ax = 0.0f, ay = 0.0f, s = 0.0f;
    for (int e = lo + slot; e < hi; e += 8) {
        float a = ex[e];
        float2 v = *(const float2*)(u2e + (long)neigh[e] * 64 + c * 2);
        ax = fmaf(a, v.x, ax);
        ay = fmaf(a, v.y, ay);
        s += a;
    }
    ax += __shfl_xor(ax, 32);
    ay += __shfl_xor(ay, 32);
    if (lane < 32) { part[wid][c * 2] = ax; part[wid][c * 2 + 1] = ay; }
    s = ((lane & 31) == 0) ? s : 0.0f;
    s += __shfl_xor(s, 32);
    s += __shfl_xor(s, 16);
    s += __shfl_xor(s, 8);
    s += __shfl_xor(s, 4);
    s += __shfl_xor(s, 2);
    s += __shfl_xor(s, 1);
    if (lane == 0) redbuf[wid] = s;
    __syncthreads();
    if (t < 64) {
        float stot = redbuf[0] + redbuf[1] + redbuf[2] + redbuf[3];
        float inv = 1.0f / fmaxf(stot, 1e-9f);
        out[(long)n * 64 + t] = (part[0][t] + part[1][t] + part[2][t] + part[3][t]) * inv;
    }
}

extern "C" void kernel_launch(void* const* d_in, const int* in_sizes, int n_in,
                              void* d_out, int out_size, void* d_ws, size_t ws_size,
                              hipStream_t stream) {
    const int* nodes = (const int*)d_in[0];
    const int* neigh = (const int*)d_in[1];
    const int* segs  = (const int*)d_in[2];
    const float* u2e = (const float*)d_in[3];
    const float* w1  = (const float*)d_in[4];
    const float* b1  = (const float*)d_in[5];
    const float* w2  = (const float*)d_in[6];
    const float* b2  = (const float*)d_in[7];
    const float* w3  = (const float*)d_in[8];
    const float* b3  = (const float*)d_in[9];
    const int N = in_sizes[0];
    const int E = in_sizes[1];
    const long VD = in_sizes[3];
    const int V = (int)(VD / 64);

    char* ws = (char*)d_ws;
    size_t off = 0;
    auto alloc = [&](size_t bytes) { char* p = ws + off; off = (off + bytes + 255) & ~(size_t)255; return p; };
    float* ex = (float*)alloc((size_t)E * 4);          // tier-3 only
    int* seg_off = (int*)alloc((size_t)(N + 1) * 4);
    unsigned short* w1t = (unsigned short*)alloc(128 * 64 * 2);
    unsigned short* w2t = (unsigned short*)alloc(64 * 64 * 2);
    size_t need_min = off;
    unsigned short* Y = (unsigned short*)alloc((size_t)VD * 2);
    unsigned short* zb = (unsigned short*)alloc((size_t)N * 64 * 2);
    size_t need_t2 = off;
    unsigned short* u2ebf = (unsigned short*)alloc((size_t)VD * 2);
    size_t need_t1 = off;

    float* out = (float*)d_out;

    prep_k<<<1, 256, 0, stream>>>(w1, w2, w1t, w2t);
    bounds_k<<<(N + 256) / 256, 256, 0, stream>>>(segs, seg_off, N, E);

    const int yblocks = ((V + 15) / 16 + 3) / 4;
    const int zblocks = ((N + 15) / 16 + 3) / 4;

    if (ws_size >= need_t1) {
        conv_y_k<<<yblocks, 256, 0, stream>>>(u2e, w1t, u2ebf, Y, V);
        z_k<true><<<zblocks, 256, 0, stream>>>(nodes, u2ebf, nullptr, w1t, b1, zb, N);
        fused_k<true><<<N, 256, 0, stream>>>(seg_off, neigh, Y, zb, u2ebf, nullptr,
                                             w2t, b2, w3, b3, out, N);
    } else if (ws_size >= need_t2) {
        y_k<<<yblocks, 256, 0, stream>>>(u2e, w1t, Y, V);
        z_k<false><<<zblocks, 256, 0, stream>>>(nodes, nullptr, u2e, w1t, b1, zb, N);
        fused_k<false><<<N, 256, 0, stream>>>(seg_off, neigh, Y, zb, nullptr, u2e,
                                              w2t, b2, w3, b3, out, N);
    } else {
        const int blocks1 = ((E + 15) / 16 + 3) / 4;
        logits_fb_k<<<blocks1, 256, 0, stream>>>(nodes, neigh, segs, u2e, w1t, w2t,
                                                 b1, b2, w3, b3, ex, E);
        agg_fb_k<<<N, 256, 0, stream>>>(seg_off, neigh, u2e, ex, out, N);
    }
}

// Round 7
// 167.702 us; speedup vs baseline: 1.4722x; 1.4722x over previous
//
#include <hip/hip_runtime.h>
#include <hip/hip_bf16.h>

typedef __attribute__((ext_vector_type(8))) short bf16x8;
typedef __attribute__((ext_vector_type(4))) float f32x4;

__device__ __forceinline__ unsigned short f2bf(float f) {
    unsigned x = __float_as_uint(f);
    unsigned r = (x + 0x7FFF + ((x >> 16) & 1)) >> 16;   // RNE
    return (unsigned short)r;
}
__device__ __forceinline__ bf16x8 cvt8(const float* __restrict__ p) {
    bf16x8 r;
#pragma unroll
    for (int j = 0; j < 8; ++j) r[j] = (short)f2bf(p[j]);
    return r;
}
__device__ __forceinline__ unsigned pack_relu_bf16(unsigned yv, unsigned zv) {
    float lo = fmaxf(__uint_as_float(yv << 16) + __uint_as_float(zv << 16), 0.0f);
    float hi = fmaxf(__uint_as_float(yv & 0xFFFF0000u) + __uint_as_float(zv & 0xFFFF0000u), 0.0f);
    __hip_bfloat162 p = __float22bfloat162_rn(float2{lo, hi});
    return *(unsigned*)&p;
}

// ---------------- kernel A: weight prep (block 0) + segment bounds (rest) -------
__global__ void prep_bounds_k(const float* __restrict__ w1,
                              const float* __restrict__ w2,
                              const int* __restrict__ segs,
                              unsigned short* __restrict__ w1t,
                              unsigned short* __restrict__ w2t,
                              int* __restrict__ seg_off, int N, int E) {
    int t = threadIdx.x;
    if (blockIdx.x == 0) {
        for (int i = t; i < 128 * 64; i += 256) {
            int k = i >> 6, n = i & 63;
            w1t[n * 128 + k] = f2bf(w1[i]);
        }
        for (int i = t; i < 64 * 64; i += 256) {
            int k = i >> 6, n = i & 63;
            w2t[n * 64 + k] = f2bf(w2[i]);
        }
    } else {
        int idx = (blockIdx.x - 1) * 256 + t;
        if (idx > N) return;
        int l = 0, r = E;
        while (l < r) { int mid = (l + r) >> 1; if (segs[mid] < idx) l = mid + 1; else r = mid; }
        seg_off[idx] = l;
    }
}

// ---------------- kernel B: [0,yblocks): u2e->bf16 + Y = u2e@W1_top ------------
//                  [yblocks,..): z[n] = u2e[nodes[n]]@W1_bot + b1   (both bf16)
template <bool BF>
__launch_bounds__(256)
__global__ void conv_y_z_k(const float* __restrict__ u2e,
                           const int* __restrict__ nodes,
                           const unsigned short* __restrict__ w1t,
                           const float* __restrict__ b1f,
                           unsigned short* __restrict__ u2ebf,
                           unsigned short* __restrict__ Y,
                           unsigned short* __restrict__ z,
                           int V, int N, int yblocks) {
    const int wid = threadIdx.x >> 6;
    const int lane = threadIdx.x & 63;
    const int q = lane >> 4;
    const int m15 = lane & 15;

    if ((int)blockIdx.x < yblocks) {
        const int wbase = (blockIdx.x * 4 + wid) * 16;
        if (wbase >= V) return;
        int row = min(wbase + m15, V - 1);
        const float* p = u2e + (long)row * 64;
        bf16x8 a0 = cvt8(p + q * 8);
        bf16x8 a1 = cvt8(p + 32 + q * 8);
        if (BF && wbase + m15 < V) {
            *(bf16x8*)(u2ebf + (long)row * 64 + q * 8) = a0;
            *(bf16x8*)(u2ebf + (long)row * 64 + 32 + q * 8) = a1;
        }
        f32x4 acc[4];
#pragma unroll
        for (int b = 0; b < 4; ++b) {
            acc[b] = (f32x4){0.f, 0.f, 0.f, 0.f};
            const bf16x8* wrow = (const bf16x8*)(w1t + (b * 16 + m15) * 128);
            acc[b] = __builtin_amdgcn_mfma_f32_16x16x32_bf16(a0, wrow[0 + q], acc[b], 0, 0, 0);
            acc[b] = __builtin_amdgcn_mfma_f32_16x16x32_bf16(a1, wrow[4 + q], acc[b], 0, 0, 0);
        }
#pragma unroll
        for (int b = 0; b < 4; ++b)
#pragma unroll
            for (int r = 0; r < 4; ++r) {
                int rr = wbase + q * 4 + r;
                if (rr < V) Y[(long)rr * 64 + b * 16 + m15] = f2bf(acc[b][r]);
            }
    } else {
        const int wbase = (((int)blockIdx.x - yblocks) * 4 + wid) * 16;
        if (wbase >= N) return;
        int nd = nodes[min(wbase + m15, N - 1)];
        const float* p = u2e + (long)nd * 64;
        bf16x8 a0 = cvt8(p + q * 8);
        bf16x8 a1 = cvt8(p + 32 + q * 8);
        f32x4 acc[4];
#pragma unroll
        for (int b = 0; b < 4; ++b) {
            float bv = b1f[b * 16 + m15];
            acc[b] = (f32x4){bv, bv, bv, bv};
            const bf16x8* wrow = (const bf16x8*)(w1t + (b * 16 + m15) * 128);
            acc[b] = __builtin_amdgcn_mfma_f32_16x16x32_bf16(a0, wrow[8 + q], acc[b], 0, 0, 0);
            acc[b] = __builtin_amdgcn_mfma_f32_16x16x32_bf16(a1, wrow[12 + q], acc[b], 0, 0, 0);
        }
#pragma unroll
        for (int b = 0; b < 4; ++b)
#pragma unroll
            for (int r = 0; r < 4; ++r) {
                int rr = wbase + q * 4 + r;
                if (rr < N) z[(long)rr * 64 + b * 16 + m15] = f2bf(acc[b][r]);
            }
    }
}

// ---------------- kernel 1: per-edge MLP, 32 edges/wave (2x16 groups) -----------
// h1 = relu(Y[neigh]+z[seg]) in-register (A-layout) -> MFMA layer2 -> layer3 ->
// ex = exp(logit). Two independent groups double memory-level parallelism.
__launch_bounds__(256)
__global__ void logits2_k(const int* __restrict__ neigh,
                          const int* __restrict__ segs,
                          const unsigned short* __restrict__ Y,
                          const unsigned short* __restrict__ z,
                          const unsigned short* __restrict__ w2t,
                          const float* __restrict__ b2f,
                          const float* __restrict__ w3f, const float* __restrict__ b3f,
                          float* __restrict__ ex, int E) {
    const int wid = threadIdx.x >> 6;
    const int lane = threadIdx.x & 63;
    const int q = lane >> 4;
    const int m15 = lane & 15;
    const long base = ((long)blockIdx.x * 4 + wid) * 32;
    if (base >= E) return;

    int vi[2], sg[2];
#pragma unroll
    for (int g = 0; g < 2; ++g) {
        long e = base + g * 16 + m15;
        int ec = (int)(e < E ? e : (long)E - 1);
        vi[g] = neigh[ec];
        sg[g] = segs[ec];
    }
    bf16x8 y0[2], y1[2], zz0[2], zz1[2];
#pragma unroll
    for (int g = 0; g < 2; ++g) {
        const unsigned short* yr = Y + (long)vi[g] * 64;
        y0[g] = *(const bf16x8*)(yr + q * 8);
        y1[g] = *(const bf16x8*)(yr + 32 + q * 8);
        const unsigned short* zr = z + (long)sg[g] * 64;
        zz0[g] = *(const bf16x8*)(zr + q * 8);
        zz1[g] = *(const bf16x8*)(zr + 32 + q * 8);
    }

    f32x4 acc[2][4];
#pragma unroll
    for (int g = 0; g < 2; ++g) {
        bf16x8 h0, h1;
#pragma unroll
        for (int j = 0; j < 4; ++j) {
            ((unsigned*)&h0)[j] = pack_relu_bf16(((unsigned*)&y0[g])[j], ((unsigned*)&zz0[g])[j]);
            ((unsigned*)&h1)[j] = pack_relu_bf16(((unsigned*)&y1[g])[j], ((unsigned*)&zz1[g])[j]);
        }
#pragma unroll
        for (int b = 0; b < 4; ++b) {
            float bv = b2f[b * 16 + m15];
            acc[g][b] = (f32x4){bv, bv, bv, bv};
            const bf16x8* wrow = (const bf16x8*)(w2t + (b * 16 + m15) * 64);
            acc[g][b] = __builtin_amdgcn_mfma_f32_16x16x32_bf16(h0, wrow[0 + q], acc[g][b], 0, 0, 0);
            acc[g][b] = __builtin_amdgcn_mfma_f32_16x16x32_bf16(h1, wrow[4 + q], acc[g][b], 0, 0, 0);
        }
    }

    const float b3v = b3f[0];
#pragma unroll
    for (int g = 0; g < 2; ++g)
#pragma unroll
        for (int r = 0; r < 4; ++r) {
            float v = 0.0f;
#pragma unroll
            for (int b = 0; b < 4; ++b) v += fmaxf(acc[g][b][r], 0.0f) * w3f[b * 16 + m15];
            v += __shfl_xor(v, 1);
            v += __shfl_xor(v, 2);
            v += __shfl_xor(v, 4);
            v += __shfl_xor(v, 8);
            long ee = base + g * 16 + q * 4 + r;
            if (m15 == r && ee < E) ex[ee] = __expf(v + b3v);
        }
}

// ---------------- kernel 2: wave-per-node weighted segment sum (no barriers) ----
// lane = slot(0..7) * 8 + cl(0..7); slot -> edge stride 8, cl -> 8 channels (16B).
template <bool BF>
__launch_bounds__(256)
__global__ void aggw_k(const int* __restrict__ seg_off,
                       const int* __restrict__ neigh,
                       const unsigned short* __restrict__ u2ebf,
                       const float* __restrict__ u2e,
                       const float* __restrict__ ex,
                       float* __restrict__ out, int N) {
    const int wid = threadIdx.x >> 6;
    const int lane = threadIdx.x & 63;
    const int n = blockIdx.x * 4 + wid;
    if (n >= N) return;
    const int lo = seg_off[n];
    const int hi = seg_off[n + 1];
    const int slot = lane >> 3;
    const int cl = lane & 7;

    float a[8] = {0.f, 0.f, 0.f, 0.f, 0.f, 0.f, 0.f, 0.f};
    float s = 0.0f;

    for (int e = lo + slot; e < hi; e += 8) {
        float w = ex[e];
        int vi = neigh[e];
        s += w;
        if constexpr (BF) {
            bf16x8 v = *(const bf16x8*)(u2ebf + (long)vi * 64 + cl * 8);
            const unsigned* vd = (const unsigned*)&v;
#pragma unroll
            for (int j = 0; j < 4; ++j) {
                a[2 * j]     = fmaf(w, __uint_as_float(vd[j] << 16), a[2 * j]);
                a[2 * j + 1] = fmaf(w, __uint_as_float(vd[j] & 0xFFFF0000u), a[2 * j + 1]);
            }
        } else {
            const float* row = u2e + (long)vi * 64 + cl * 8;
            float4 v0 = *(const float4*)row;
            float4 v1 = *(const float4*)(row + 4);
            a[0] = fmaf(w, v0.x, a[0]); a[1] = fmaf(w, v0.y, a[1]);
            a[2] = fmaf(w, v0.z, a[2]); a[3] = fmaf(w, v0.w, a[3]);
            a[4] = fmaf(w, v1.x, a[4]); a[5] = fmaf(w, v1.y, a[5]);
            a[6] = fmaf(w, v1.z, a[6]); a[7] = fmaf(w, v1.w, a[7]);
        }
    }
    // fold across the 8 slots (lane bits 3..5); cl dimension untouched
#pragma unroll
    for (int msk = 8; msk <= 32; msk <<= 1) {
        s += __shfl_xor(s, msk);
#pragma unroll
        for (int j = 0; j < 8; ++j) a[j] += __shfl_xor(a[j], msk);
    }
    if (slot == 0) {
        float inv = 1.0f / fmaxf(s, 1e-9f);
        float4 o0 = {a[0] * inv, a[1] * inv, a[2] * inv, a[3] * inv};
        float4 o1 = {a[4] * inv, a[5] * inv, a[6] * inv, a[7] * inv};
        float* op = out + (long)n * 64 + cl * 8;
        *(float4*)op = o0;
        *(float4*)(op + 4) = o1;
    }
}

// ---------------- tier-3 fallback (tiny ws) -------------------------------------
__launch_bounds__(256)
__global__ void logits_fb_k(const int* __restrict__ nodes,
                            const int* __restrict__ neigh,
                            const int* __restrict__ segs,
                            const float* __restrict__ u2e,
                            const unsigned short* __restrict__ w1t,
                            const unsigned short* __restrict__ w2t,
                            const float* __restrict__ b1f, const float* __restrict__ b2f,
                            const float* __restrict__ w3f, const float* __restrict__ b3f,
                            float* __restrict__ ex, int E) {
    __shared__ __align__(16) unsigned short h1buf[4][16 * 72];
    const int wid = threadIdx.x >> 6;
    const int lane = threadIdx.x & 63;
    const int q = lane >> 4;
    const int m15 = lane & 15;
    const long base = ((long)blockIdx.x * 4 + wid) * 16;
    long ee0 = base + m15;
    int e = (int)(ee0 < E ? ee0 : (long)E - 1);
    int ni = neigh[e];
    int ctr = nodes[segs[e]];
    const float* eu = u2e + (long)ni * 64;
    const float* ur = u2e + (long)ctr * 64;
    bf16x8 a0 = cvt8(eu + q * 8), a1 = cvt8(eu + 32 + q * 8);
    bf16x8 a2 = cvt8(ur + q * 8), a3 = cvt8(ur + 32 + q * 8);
    f32x4 acc[4];
#pragma unroll
    for (int b = 0; b < 4; ++b) {
        float bv = b1f[b * 16 + m15];
        acc[b] = (f32x4){bv, bv, bv, bv};
        const bf16x8* wrow = (const bf16x8*)(w1t + (b * 16 + m15) * 128);
        acc[b] = __builtin_amdgcn_mfma_f32_16x16x32_bf16(a0, wrow[0 + q], acc[b], 0, 0, 0);
        acc[b] = __builtin_amdgcn_mfma_f32_16x16x32_bf16(a1, wrow[4 + q], acc[b], 0, 0, 0);
        acc[b] = __builtin_amdgcn_mfma_f32_16x16x32_bf16(a2, wrow[8 + q], acc[b], 0, 0, 0);
        acc[b] = __builtin_amdgcn_mfma_f32_16x16x32_bf16(a3, wrow[12 + q], acc[b], 0, 0, 0);
    }
#pragma unroll
    for (int b = 0; b < 4; ++b)
#pragma unroll
        for (int r = 0; r < 4; ++r)
            h1buf[wid][(q * 4 + r) * 72 + b * 16 + m15] = f2bf(fmaxf(acc[b][r], 0.0f));
    const unsigned short* hrow = &h1buf[wid][m15 * 72];
    bf16x8 h0 = *(const bf16x8*)(hrow + q * 8);
    bf16x8 h1 = *(const bf16x8*)(hrow + 32 + q * 8);
    f32x4 acc2[4];
#pragma unroll
    for (int b = 0; b < 4; ++b) {
        float bv = b2f[b * 16 + m15];
        acc2[b] = (f32x4){bv, bv, bv, bv};
        const bf16x8* wrow = (const bf16x8*)(w2t + (b * 16 + m15) * 64);
        acc2[b] = __builtin_amdgcn_mfma_f32_16x16x32_bf16(h0, wrow[0 + q], acc2[b], 0, 0, 0);
        acc2[b] = __builtin_amdgcn_mfma_f32_16x16x32_bf16(h1, wrow[4 + q], acc2[b], 0, 0, 0);
    }
    float b3v = b3f[0];
#pragma unroll
    for (int r = 0; r < 4; ++r) {
        float v = 0.0f;
#pragma unroll
        for (int b = 0; b < 4; ++b) v += fmaxf(acc2[b][r], 0.0f) * w3f[b * 16 + m15];
        v += __shfl_xor(v, 1);
        v += __shfl_xor(v, 2);
        v += __shfl_xor(v, 4);
        v += __shfl_xor(v, 8);
        long ee = base + q * 4 + r;
        if (m15 == r && ee < E) ex[ee] = __expf(v + b3v);
    }
}

extern "C" void kernel_launch(void* const* d_in, const int* in_sizes, int n_in,
                              void* d_out, int out_size, void* d_ws, size_t ws_size,
                              hipStream_t stream) {
    const int* nodes = (const int*)d_in[0];
    const int* neigh = (const int*)d_in[1];
    const int* segs  = (const int*)d_in[2];
    const float* u2e = (const float*)d_in[3];
    const float* w1  = (const float*)d_in[4];
    const float* b1  = (const float*)d_in[5];
    const float* w2  = (const float*)d_in[6];
    const float* b2  = (const float*)d_in[7];
    const float* w3  = (const float*)d_in[8];
    const float* b3  = (const float*)d_in[9];
    const int N = in_sizes[0];
    const int E = in_sizes[1];
    const long VD = in_sizes[3];
    const int V = (int)(VD / 64);

    char* ws = (char*)d_ws;
    size_t off = 0;
    auto alloc = [&](size_t bytes) { char* p = ws + off; off = (off + bytes + 255) & ~(size_t)255; return p; };
    float* ex = (float*)alloc((size_t)E * 4);
    int* seg_off = (int*)alloc((size_t)(N + 1) * 4);
    unsigned short* w1t = (unsigned short*)alloc(128 * 64 * 2);
    unsigned short* w2t = (unsigned short*)alloc(64 * 64 * 2);
    size_t need_min = off;
    unsigned short* Y = (unsigned short*)alloc((size_t)VD * 2);
    unsigned short* zb = (unsigned short*)alloc((size_t)N * 64 * 2);
    size_t need_t2 = off;
    unsigned short* u2ebf = (unsigned short*)alloc((size_t)VD * 2);
    size_t need_t1 = off;
    (void)need_min;

    float* out = (float*)d_out;

    const int pbblocks = 1 + (N + 256) / 256;
    prep_bounds_k<<<pbblocks, 256, 0, stream>>>(w1, w2, segs, w1t, w2t, seg_off, N, E);

    const int yblocks = ((V + 15) / 16 + 3) / 4;
    const int zblocks = ((N + 15) / 16 + 3) / 4;
    const int lblocks = ((E + 31) / 32 + 3) / 4;
    const int ablocks = (N + 3) / 4;

    if (ws_size >= need_t1) {
        conv_y_z_k<true><<<yblocks + zblocks, 256, 0, stream>>>(
            u2e, nodes, w1t, b1, u2ebf, Y, zb, V, N, yblocks);
        logits2_k<<<lblocks, 256, 0, stream>>>(neigh, segs, Y, zb, w2t, b2, w3, b3, ex, E);
        aggw_k<true><<<ablocks, 256, 0, stream>>>(seg_off, neigh, u2ebf, nullptr, ex, out, N);
    } else if (ws_size >= need_t2) {
        conv_y_z_k<false><<<yblocks + zblocks, 256, 0, stream>>>(
            u2e, nodes, w1t, b1, nullptr, Y, zb, V, N, yblocks);
        logits2_k<<<lblocks, 256, 0, stream>>>(neigh, segs, Y, zb, w2t, b2, w3, b3, ex, E);
        aggw_k<false><<<ablocks, 256, 0, stream>>>(seg_off, neigh, nullptr, u2e, ex, out, N);
    } else {
        const int blocks1 = ((E + 15) / 16 + 3) / 4;
        logits_fb_k<<<blocks1, 256, 0, stream>>>(nodes, neigh, segs, u2e, w1t, w2t,
                                                 b1, b2, w3, b3, ex, E);
        aggw_k<false><<<ablocks, 256, 0, stream>>>(seg_off, neigh, nullptr, u2e, ex, out, N);
    }
}